// Round 14
// baseline (755.038 us; speedup 1.0000x reference)
//
#include <hip/hip_runtime.h>

typedef __bf16 bf16;
typedef __bf16 bf16x4 __attribute__((ext_vector_type(4)));
typedef __bf16 bf16x8 __attribute__((ext_vector_type(8)));
typedef float f32x4 __attribute__((ext_vector_type(4)));

#define BM 128
#define BN 128
#define BK 32

// ---------------- async global->LDS (16B per lane) ----------------
__device__ __forceinline__ void async16(const void* g, void* l) {
    __builtin_amdgcn_global_load_lds(
        (__attribute__((address_space(1))) void*)g,
        (__attribute__((address_space(3))) void*)l,
        16, 0, 0);
}

// =============================================================================
// Proj GEMM R14 (= R13 with the ph4 quadrant bug fixed): faithful 8-phase
// port. 256^2, BK=64, 8 waves, dbuf (b0 = even tiles, b1 = odd).
// Per phase: {stage 1 half-tile (2 gloads); [vmcnt(6) at ph0/ph4]; barrier;
// [ds_read frags]; setprio(1) 16 MFMA setprio(0); barrier}.
// Wave (wm,wn) reads ONLY A-half wm and B-half wn>>1; all 24 frag reads for
// a tile front-loaded into its first 2 phases, register-held -> buffer
// halves die early -> 1 half-tile staged per phase, 4-6 phases ahead of use.
// FIFO ledger (2 loads/HT), verified by induction:
//   stage order/iter: ph0:O.B0 ph1:O.B1 ph2:E'.A0 ph3:E'.A1 ph4:E'.B0
//                     ph5:E'.B1 ph6:O'.A0 ph7:O'.A1
//   ph0 vmcnt(6): outstanding = O.A0,O.A1(prev ph6,7)+O.B0 = 6 -> E drained.
//   ph4 vmcnt(6): outstanding = E'.A0,A1,B0 = 6 -> O drained.
//   Last iter: ph4 vmcnt(0). Quadrants: (0,0)a0,(1,0)a1,(1,1)a1,(0,1)a0 for
// BOTH parities (acc indexed by output quadrant; K accumulates).
// Write hazards: each stage target's last reader >=2 barriers upstream.
// Epilogue: LDS-transpose (XOR swizzle) + NT contiguous f32x4 stores (R4).
// =============================================================================
__global__ __launch_bounds__(512, 2) void gemm8p(
    const bf16* __restrict__ A, const bf16* __restrict__ W,
    float* __restrict__ C, int K, int ldo, int Nstore, int nTilesM)
{
    __shared__ bf16 lds[2][32768];   // [buf][A 16384 | B 16384] = 128 KiB

    // bijective XCD swizzle (m204) + m-fastest ordering for W-panel L2 reuse
    int nwg = gridDim.x;
    int orig = blockIdx.x;
    int q = nwg >> 3, r = nwg & 7, xcd = orig & 7, local = orig >> 3;
    int wgid = (xcd < r ? xcd * (q + 1) : r * (q + 1) + (xcd - r) * q) + local;
    const int brow = (wgid % nTilesM) * 256;
    const int bcol = (wgid / nTilesM) * 256;

    const int t = threadIdx.x;
    const int wid = t >> 6, lane = t & 63;
    const int wm = wid >> 2, wn = wid & 3;
    const int l15 = lane & 15, l7 = lane & 7, lhi = lane >> 4;

    // staging source: 64-row units, 8 chunks/row, inverse-swizzled chunk
    const int lr = t >> 3;                 // 0..63
    const int cc = (t & 7) ^ (lr & 7);
    const bf16* gA = A + (size_t)(brow + lr) * K + cc * 8;
    const bf16* gW = W + (size_t)(bcol + lr) * K + cc * 8;
    const int dsto = wid * 512;            // wave-uniform LDS base (HW adds lane*16B)

    // fragment read constants (elements)
    const int kx0 = (lhi ^ l7) * 8;
    const int kx1 = ((4 + lhi) ^ l7) * 8;
    const int abase = wm * 8192 + l15 * 64;             // A-half = wm
    const int bbase = 16384 + (wn >> 1) * 8192 + ((wn & 1) * 64 + l15) * 64;

    f32x4 acc[8][4] = {};
    const int nkt = K >> 6;                // 12 for K=768 (even)

    // half-tile stages (2 gloads each)
    #define SA0(d, k0) { async16(gA + (k0), (d) + dsto); \
                         async16(gA + (size_t)64*K + (k0), (d) + 4096 + dsto); }
    #define SA1(d, k0) { async16(gA + (size_t)128*K + (k0), (d) + 8192 + dsto); \
                         async16(gA + (size_t)192*K + (k0), (d) + 12288 + dsto); }
    #define SB0(d, k0) { async16(gW + (k0), (d) + 16384 + dsto); \
                         async16(gW + (size_t)64*K + (k0), (d) + 20480 + dsto); }
    #define SB1(d, k0) { async16(gW + (size_t)128*K + (k0), (d) + 24576 + dsto); \
                         async16(gW + (size_t)192*K + (k0), (d) + 28672 + dsto); }

    bf16* b0 = &lds[0][0];
    bf16* b1 = &lds[1][0];

    // prologue: tile0 full -> b0 (4 HT); tile1 A-halves -> b1 (2 HT)
    SA0(b0, 0) SA1(b0, 0) SB0(b0, 0) SB1(b0, 0)
    SA0(b1, 64) SA1(b1, 64)

    bf16x8 a0[4][2], a1[4][2], b[4][2];
    const int niter = nkt >> 1;            // 6

    #define MFMA16(QM, QN, AR)                                                  \
        __builtin_amdgcn_s_setprio(1);                                          \
        _Pragma("unroll")                                                       \
        for (int fi = 0; fi < 4; fi++)                                          \
            _Pragma("unroll")                                                   \
            for (int fj = 0; fj < 2; fj++) {                                    \
                f32x4 c0 = acc[(QM)*4 + fi][(QN)*2 + fj];                       \
                c0 = __builtin_amdgcn_mfma_f32_16x16x32_bf16(                   \
                        AR[fi][0], b[(QN)*2 + fj][0], c0, 0, 0, 0);             \
                c0 = __builtin_amdgcn_mfma_f32_16x16x32_bf16(                   \
                        AR[fi][1], b[(QN)*2 + fj][1], c0, 0, 0, 0);             \
                acc[(QM)*4 + fi][(QN)*2 + fj] = c0;                             \
            }                                                                   \
        __builtin_amdgcn_s_setprio(0);

    for (int it = 0; it < niter; ++it) {
        const int kO  = (2 * it + 1) << 6;
        const int kE2 = (2 * it + 2) << 6;
        const int kO2 = (2 * it + 3) << 6;
        const bool sE2 = (2 * it + 2) < nkt;
        const bool sO2 = (2 * it + 3) < nkt;

        // ---- ph0: stage O.B0; vmcnt(6) publishes E; read E a0 + b(qn0..1)
        SB0(b1, kO)
        asm volatile("s_waitcnt vmcnt(6)" ::: "memory");
        __builtin_amdgcn_s_barrier();
        #pragma unroll
        for (int fi = 0; fi < 4; fi++) {
            a0[fi][0] = *(const bf16x8*)(b0 + abase + fi * 1024 + kx0);
            a0[fi][1] = *(const bf16x8*)(b0 + abase + fi * 1024 + kx1);
        }
        #pragma unroll
        for (int fj = 0; fj < 2; fj++) {
            b[fj][0] = *(const bf16x8*)(b0 + bbase + fj * 1024 + kx0);
            b[fj][1] = *(const bf16x8*)(b0 + bbase + fj * 1024 + kx1);
        }
        MFMA16(0, 0, a0)
        __builtin_amdgcn_s_barrier();

        // ---- ph1: read E a1 + b(qn2..3); stage O.B1
        #pragma unroll
        for (int fi = 0; fi < 4; fi++) {
            a1[fi][0] = *(const bf16x8*)(b0 + abase + 4096 + fi * 1024 + kx0);
            a1[fi][1] = *(const bf16x8*)(b0 + abase + 4096 + fi * 1024 + kx1);
        }
        #pragma unroll
        for (int fj = 2; fj < 4; fj++) {
            b[fj][0] = *(const bf16x8*)(b0 + bbase + fj * 1024 + kx0);
            b[fj][1] = *(const bf16x8*)(b0 + bbase + fj * 1024 + kx1);
        }
        SB1(b1, kO)
        __builtin_amdgcn_s_barrier();
        MFMA16(1, 0, a1)
        __builtin_amdgcn_s_barrier();

        // ---- ph2: b0.A dead -> stage E'.A0; MFMA E Q(1,1)
        if (sE2) { SA0(b0, kE2) }
        __builtin_amdgcn_s_barrier();
        MFMA16(1, 1, a1)
        __builtin_amdgcn_s_barrier();

        // ---- ph3: stage E'.A1; MFMA E Q(0,1)
        if (sE2) { SA1(b0, kE2) }
        __builtin_amdgcn_s_barrier();
        MFMA16(0, 1, a0)
        __builtin_amdgcn_s_barrier();

        // ---- ph4: stage E'.B0; vmcnt publishes O; read O a0 + b(qn0..1)
        if (sE2) {
            SB0(b0, kE2)
            asm volatile("s_waitcnt vmcnt(6)" ::: "memory");
        } else {
            asm volatile("s_waitcnt vmcnt(0)" ::: "memory");
        }
        __builtin_amdgcn_s_barrier();
        #pragma unroll
        for (int fi = 0; fi < 4; fi++) {
            a0[fi][0] = *(const bf16x8*)(b1 + abase + fi * 1024 + kx0);
            a0[fi][1] = *(const bf16x8*)(b1 + abase + fi * 1024 + kx1);
        }
        #pragma unroll
        for (int fj = 0; fj < 2; fj++) {
            b[fj][0] = *(const bf16x8*)(b1 + bbase + fj * 1024 + kx0);
            b[fj][1] = *(const bf16x8*)(b1 + bbase + fj * 1024 + kx1);
        }
        MFMA16(0, 0, a0)                 // R13 bug was here (computed Q(1,0))
        __builtin_amdgcn_s_barrier();

        // ---- ph5: read O a1 + b(qn2..3); stage E'.B1
        #pragma unroll
        for (int fi = 0; fi < 4; fi++) {
            a1[fi][0] = *(const bf16x8*)(b1 + abase + 4096 + fi * 1024 + kx0);
            a1[fi][1] = *(const bf16x8*)(b1 + abase + 4096 + fi * 1024 + kx1);
        }
        #pragma unroll
        for (int fj = 2; fj < 4; fj++) {
            b[fj][0] = *(const bf16x8*)(b1 + bbase + fj * 1024 + kx0);
            b[fj][1] = *(const bf16x8*)(b1 + bbase + fj * 1024 + kx1);
        }
        if (sE2) { SB1(b0, kE2) }
        __builtin_amdgcn_s_barrier();
        MFMA16(1, 0, a1)
        __builtin_amdgcn_s_barrier();

        // ---- ph6: b1.A dead -> stage O'.A0; MFMA O Q(1,1)
        if (sO2) { SA0(b1, kO2) }
        __builtin_amdgcn_s_barrier();
        MFMA16(1, 1, a1)
        __builtin_amdgcn_s_barrier();

        // ---- ph7: stage O'.A1; MFMA O Q(0,1)
        if (sO2) { SA1(b1, kO2) }
        __builtin_amdgcn_s_barrier();
        MFMA16(0, 1, a0)
        __builtin_amdgcn_s_barrier();
    }
    #undef MFMA16
    #undef SA0
    #undef SA1
    #undef SB0
    #undef SB1

    // ---- epilogue: LDS transpose (XOR swizzle) -> contiguous NT f32x4 stores
    float* ldsf = (float*)&lds[0][0];
    const int lhi4 = lhi * 4;
    #pragma unroll
    for (int h = 0; h < 2; h++) {
        if (h) __builtin_amdgcn_s_barrier();  // h0 gather reads consumed
        #pragma unroll
        for (int fi4 = 0; fi4 < 4; fi4++) {
            #pragma unroll
            for (int fj = 0; fj < 4; fj++) {
                f32x4 v = acc[h * 4 + fi4][fj];
                int row0 = wm * 64 + fi4 * 16 + lhi4;
                int col = wn * 64 + fj * 16 + l15;
                #pragma unroll
                for (int r2 = 0; r2 < 4; r2++) {
                    int row = row0 + r2;
                    ldsf[row * 256 + (col ^ ((row & 12) << 1))] = v[r2];
                }
            }
        }
        __builtin_amdgcn_s_barrier();
        #pragma unroll
        for (int i = 0; i < 16; i++) {
            int c = i * 512 + t;               // 0..8191 chunks of 16B
            int row = c >> 6, ch = c & 63;
            f32x4 v = *(const f32x4*)(ldsf + row * 256
                                      + ((ch ^ ((row & 12) >> 1)) << 2));
            int grow = brow + (row >> 6) * 128 + h * 64 + (row & 63);
            int gcol = bcol + ch * 4;
            float* dst = C + (size_t)grow * ldo + gcol;
            if (gcol + 4 <= Nstore) {
                __builtin_nontemporal_store(v, (f32x4*)dst);
            } else {
                #pragma unroll
                for (int k2 = 0; k2 < 4; k2++)
                    if (gcol + k2 < Nstore) dst[k2] = v[k2];
            }
        }
    }
}

// =============================================================================
// Small-GEMM kernel (128^2, dbuf deep-slack — R12 version, passed)
// =============================================================================
__global__ __launch_bounds__(256) void gemm_bt(
    const bf16* __restrict__ A, const bf16* __restrict__ W,
    const float* __restrict__ bias,
    float* __restrict__ outF, bf16* __restrict__ outB,
    int M, int K, int ldo, int Nstore, int relu)
{
    __shared__ bf16 As[2][4096];
    __shared__ bf16 Ws[2][4096];
    const int brow = blockIdx.y * BM;
    const int bcol = blockIdx.x * BN;
    const int t = threadIdx.x;
    const int wv = t >> 6;
    const int lane = t & 63;
    const int wrow = (wv >> 1) * 64;
    const int wcol = (wv & 1) * 64;

    f32x4 acc[4][4] = {};

    const int row0 = t >> 2;
    const int cg = (t & 3) * 8;
    const bf16* gA = A + (size_t)(brow + row0) * K + cg;
    const bf16* gW = W + (size_t)(bcol + row0) * K + cg;
    const size_t rstep = (size_t)64 * K;
    const int dsto = wv * 512;

    const int lrow = lane & 15;
    const int kg = (lane >> 4) * 8;

    #define ST(buf, k0)                                   \
        async16(gA + (k0), &As[buf][0] + dsto);           \
        async16(gA + rstep + (k0), &As[buf][2048] + dsto);\
        async16(gW + (k0), &Ws[buf][0] + dsto);           \
        async16(gW + rstep + (k0), &Ws[buf][2048] + dsto);

    const int nkt = K >> 5;
    ST(0, 0);
    for (int kt = 0; kt < nkt; ++kt) {
        const int cur = kt & 1;
        if (kt + 1 < nkt) {
            ST(cur ^ 1, (kt + 1) << 5);
            asm volatile("s_waitcnt vmcnt(4)" ::: "memory");
        } else {
            asm volatile("s_waitcnt vmcnt(0)" ::: "memory");
        }
        __builtin_amdgcn_s_barrier();
        bf16x8 af[4], wf[4];
        #pragma unroll
        for (int i = 0; i < 4; i++)
            af[i] = *(const bf16x8*)(&As[cur][0] + (wrow + i * 16 + lrow) * BK + kg);
        #pragma unroll
        for (int j = 0; j < 4; j++)
            wf[j] = *(const bf16x8*)(&Ws[cur][0] + (wcol + j * 16 + lrow) * BK + kg);
        __builtin_amdgcn_s_setprio(1);
        #pragma unroll
        for (int i = 0; i < 4; i++)
            #pragma unroll
            for (int j = 0; j < 4; j++)
                acc[i][j] = __builtin_amdgcn_mfma_f32_16x16x32_bf16(
                    af[i], wf[j], acc[i][j], 0, 0, 0);
        __builtin_amdgcn_s_setprio(0);
        __builtin_amdgcn_s_barrier();
    }
    #undef ST

    const int lcol = lane & 15;
    const int rb = (lane >> 4) * 4;
    #pragma unroll
    for (int j = 0; j < 4; j++) {
        int n = bcol + wcol + j * 16 + lcol;
        if (n >= Nstore) continue;
        float bv = bias ? bias[n] : 0.f;
        #pragma unroll
        for (int i = 0; i < 4; i++) {
            #pragma unroll
            for (int r = 0; r < 4; r++) {
                int m = brow + wrow + i * 16 + rb + r;
                float v = acc[i][j][r] + bv;
                if (relu) v = fmaxf(v, 0.f);
                size_t off = (size_t)m * ldo + n;
                if (outF) outF[off] = v;
                if (outB) outB[off] = (bf16)v;
            }
        }
    }
}

// ---------------- fp32 -> bf16 convert (zero-pads rows beyond nvalid) --------
__global__ __launch_bounds__(256) void cvt_bf16(
    const float* __restrict__ in, bf16* __restrict__ out,
    size_t nvalid, size_t ntotal)
{
    size_t i = ((size_t)blockIdx.x * 256 + threadIdx.x) * 4;
    if (i >= ntotal) return;
    bf16x4 r;
    if (i < nvalid) {
        f32x4 f = __builtin_nontemporal_load((const f32x4*)(in + i));
        r[0] = (bf16)f[0]; r[1] = (bf16)f[1]; r[2] = (bf16)f[2]; r[3] = (bf16)f[3];
    } else {
        r[0] = (bf16)0.f; r[1] = (bf16)0.f; r[2] = (bf16)0.f; r[3] = (bf16)0.f;
    }
    *(bf16x4*)(out + i) = r;
}

// ---------------- build tgt = [start, emb[tok0], emb[tok1]] per sequence -----
__global__ __launch_bounds__(256) void build_tgt(
    const float* __restrict__ start, const float* __restrict__ emb,
    const int* __restrict__ toks, float* __restrict__ outF, bf16* __restrict__ outB)
{
    int r = blockIdx.x;               // 0..3071, r = n*3 + p
    int n = r / 3, p = r % 3;
    const float* src = (p == 0) ? start : emb + (size_t)toks[n * 3 + (p - 1)] * 768;
    int t = threadIdx.x;
    #pragma unroll
    for (int j = 0; j < 3; j++) {
        int c = t + j * 256;
        float v = src[c];
        outF[(size_t)r * 768 + c] = v;
        outB[(size_t)r * 768 + c] = (bf16)v;
    }
}

// ---------------- 3-token causal self-attention, one wave per (n,head) -------
__global__ __launch_bounds__(64) void attn3(
    const float* __restrict__ qkv, bf16* __restrict__ o)
{
    int blk = blockIdx.x;             // n*4 + h
    int n = blk >> 2, h = blk & 3;
    int lane = threadIdx.x;
    const float* base = qkv + (size_t)n * 3 * 2304 + h * 192;
    float q[3][3], k[3][3], v[3][3];
    #pragma unroll
    for (int p = 0; p < 3; p++)
        #pragma unroll
        for (int j = 0; j < 3; j++) {
            int d = lane + j * 64;
            q[p][j] = base[p * 2304 + d];
            k[p][j] = base[p * 2304 + 768 + d];
            v[p][j] = base[p * 2304 + 1536 + d];
        }
    float s[3][3];
    #pragma unroll
    for (int p = 0; p < 3; p++)
        #pragma unroll
        for (int pk = 0; pk < 3; pk++) {
            if (pk > p) continue;
            float ps = q[p][0] * k[pk][0] + q[p][1] * k[pk][1] + q[p][2] * k[pk][2];
            #pragma unroll
            for (int off = 32; off; off >>= 1) ps += __shfl_xor(ps, off);
            s[p][pk] = ps * 0.072168783648703220563f;   // 1/sqrt(192)
        }
    float a[3][3] = {};
    a[0][0] = 1.f;
    {
        float m = fmaxf(s[1][0], s[1][1]);
        float e0 = expf(s[1][0] - m), e1 = expf(s[1][1] - m);
        float inv = 1.f / (e0 + e1);
        a[1][0] = e0 * inv; a[1][1] = e1 * inv;
    }
    {
        float m = fmaxf(fmaxf(s[2][0], s[2][1]), s[2][2]);
        float e0 = expf(s[2][0] - m), e1 = expf(s[2][1] - m), e2 = expf(s[2][2] - m);
        float inv = 1.f / (e0 + e1 + e2);
        a[2][0] = e0 * inv; a[2][1] = e1 * inv; a[2][2] = e2 * inv;
    }
    bf16* ob = o + (size_t)n * 3 * 768 + h * 192;
    #pragma unroll
    for (int p = 0; p < 3; p++)
        #pragma unroll
        for (int j = 0; j < 3; j++) {
            float val = a[p][0] * v[0][j];
            if (p >= 1) val += a[p][1] * v[1][j];
            if (p >= 2) val += a[p][2] * v[2][j];
            ob[p * 768 + lane + j * 64] = (bf16)val;
        }
}

// ---------------- x = LN(a + b) ; b optionally broadcast over 3 positions ----
__global__ __launch_bounds__(256) void add_ln(
    const float* __restrict__ a, const float* __restrict__ b,
    const float* __restrict__ g, const float* __restrict__ be,
    float* __restrict__ outF, bf16* __restrict__ outB, int bcast)
{
    int r = blockIdx.x;
    int t = threadIdx.x;
    const float* ar = a + (size_t)r * 768;
    const float* br = b + (size_t)(bcast ? (r / 3) : r) * 768;
    float x[3];
    float s = 0.f, sq = 0.f;
    #pragma unroll
    for (int j = 0; j < 3; j++) {
        int c = t + j * 256;
        x[j] = ar[c] + br[c];
        s += x[j]; sq += x[j] * x[j];
    }
    #pragma unroll
    for (int off = 32; off; off >>= 1) {
        s += __shfl_xor(s, off);
        sq += __shfl_xor(sq, off);
    }
    __shared__ float ls[4], lq[4];
    int wv = t >> 6;
    if ((t & 63) == 0) { ls[wv] = s; lq[wv] = sq; }
    __syncthreads();
    s = ls[0] + ls[1] + ls[2] + ls[3];
    sq = lq[0] + lq[1] + lq[2] + lq[3];
    float mean = s * (1.f / 768.f);
    float var = sq * (1.f / 768.f) - mean * mean;
    float inv = rsqrtf(var + 1e-5f);
    #pragma unroll
    for (int j = 0; j < 3; j++) {
        int c = t + j * 256;
        float y = (x[j] - mean) * inv * g[c] + be[c];
        if (outF) outF[(size_t)r * 768 + c] = y;
        if (outB) outB[(size_t)r * 768 + c] = (bf16)y;
    }
}

// =============================================================================
static inline void run_gemm(const bf16* A, const bf16* W, const float* bias,
                            float* outF, bf16* outB, int M, int Npad, int K,
                            int ldo, int Nstore, int relu, hipStream_t s)
{
    dim3 grid(Npad / BN, M / BM);
    gemm_bt<<<grid, 256, 0, s>>>(A, W, bias, outF, outB, M, K, ldo, Nstore, relu);
}

static inline void run_cvt(const float* in, bf16* out, size_t nvalid,
                           size_t ntotal, hipStream_t s)
{
    int blocks = (int)((ntotal / 4 + 255) / 256);
    cvt_bf16<<<blocks, 256, 0, s>>>(in, out, nvalid, ntotal);
}

extern "C" void kernel_launch(void* const* d_in, const int* in_sizes, int n_in,
                              void* d_out, int out_size, void* d_ws, size_t ws_size,
                              hipStream_t stream)
{
    const float* enc      = (const float*)d_in[0];   // (1024, 768)
    const int*   toks     = (const int*)d_in[1];     // (1024, 3)
    const float* start    = (const float*)d_in[2];   // (1, 768)
    const float* emb      = (const float*)d_in[3];   // (51865, 768)
    const float* sa_in_w  = (const float*)d_in[4];   // (2304, 768)
    const float* sa_in_b  = (const float*)d_in[5];
    const float* sa_out_w = (const float*)d_in[6];   // (768, 768)
    const float* sa_out_b = (const float*)d_in[7];
    const float* ca_in_w  = (const float*)d_in[8];   // (2304, 768); only Wv used
    const float* ca_in_b  = (const float*)d_in[9];
    const float* ca_out_w = (const float*)d_in[10];  // (768, 768)
    const float* ca_out_b = (const float*)d_in[11];
    const float* lin1_w   = (const float*)d_in[12];  // (2048, 768)
    const float* lin1_b   = (const float*)d_in[13];
    const float* lin2_w   = (const float*)d_in[14];  // (768, 2048)
    const float* lin2_b   = (const float*)d_in[15];
    const float* ln1_g    = (const float*)d_in[16];
    const float* ln1_bb   = (const float*)d_in[17];
    const float* ln2_g    = (const float*)d_in[18];
    const float* ln2_bb   = (const float*)d_in[19];
    const float* ln3_g    = (const float*)d_in[20];
    const float* ln3_bb   = (const float*)d_in[21];
    const float* proj_w   = (const float*)d_in[22];  // (51865, 768)
    float* out = (float*)d_out;

    const int NTOK = 3072;          // B*T*NT
    const int NM   = 1024;          // B*T
    const int H    = 768;
    const int V    = 51865;
    const int VPAD = 51968;         // 203*256
    const int DFF  = 2048;

    char* p = (char*)d_ws;
    auto alloc = [&](size_t bytes) {
        void* r = (void*)p;
        p += (bytes + 255) & ~(size_t)255;
        return r;
    };
    float* tgt_f = (float*)alloc((size_t)NTOK * H * 4);
    float* x1_f  = (float*)alloc((size_t)NTOK * H * 4);
    float* x2_f  = (float*)alloc((size_t)NTOK * H * 4);
    float* big_f = (float*)alloc((size_t)NTOK * 2304 * 4);  // qkv / gemm fp32 outs
    bf16*  actA  = (bf16*)alloc((size_t)NTOK * 2304 * 2);   // bf16 activations A
    bf16*  actB  = (bf16*)alloc((size_t)NTOK * DFF * 2);    // bf16 activations B
    bf16*  Wbf   = (bf16*)alloc((size_t)VPAD * H * 2);      // bf16 weights (reused)
    bf16*  mem_bf = actB;                                   // (1024,768) carved
    bf16*  v_bf   = actB + (size_t)NM * H;                  // (1024,768) carved
    float* cao_f  = big_f + (size_t)NTOK * H;               // (1024,768) carved

    // 1. tgt = [start, emb[t0], emb[t1]]
    build_tgt<<<NTOK, 256, 0, stream>>>(start, emb, toks, tgt_f, actA);

    // 2. qkv = tgt @ sa_in_w.T + b       (3072 x 2304)
    run_cvt(sa_in_w, Wbf, (size_t)2304 * H, (size_t)2304 * H, stream);
    run_gemm(actA, Wbf, sa_in_b, big_f, nullptr, NTOK, 2304, H, 2304, 2304, 0, stream);

    // 3. 3x3 causal attention -> o (bf16)
    attn3<<<NM * 4, 64, 0, stream>>>(big_f, actA);

    // 4. sa = o @ sa_out_w.T + b
    run_cvt(sa_out_w, Wbf, (size_t)H * H, (size_t)H * H, stream);
    run_gemm(actA, Wbf, sa_out_b, big_f, nullptr, NTOK, H, H, H, H, 0, stream);

    // 5. x1 = LN1(tgt + sa)
    add_ln<<<NTOK, 256, 0, stream>>>(tgt_f, big_f, ln1_g, ln1_bb, x1_f, nullptr, 0);

    // 6. cross-attn (Lk=1 => softmax==1 => output == V projection of memory)
    run_cvt(enc, mem_bf, (size_t)NM * H, (size_t)NM * H, stream);
    run_cvt(ca_in_w + (size_t)1536 * H, Wbf, (size_t)H * H, (size_t)H * H, stream);
    run_gemm(mem_bf, Wbf, ca_in_b + 1536, nullptr, v_bf, NM, H, H, H, H, 0, stream);
    run_cvt(ca_out_w, Wbf, (size_t)H * H, (size_t)H * H, stream);
    run_gemm(v_bf, Wbf, ca_out_b, cao_f, nullptr, NM, H, H, H, H, 0, stream);

    // 7. x2 = LN2(x1 + ca_out[broadcast])
    add_ln<<<NTOK, 256, 0, stream>>>(x1_f, cao_f, ln2_g, ln2_bb, x2_f, actA, 1);

    // 8. ff1 = relu(x2 @ lin1_w.T + b)   (bf16 only)
    run_cvt(lin1_w, Wbf, (size_t)DFF * H, (size_t)DFF * H, stream);
    run_gemm(actA, Wbf, lin1_b, nullptr, actB, NTOK, DFF, H, DFF, DFF, 1, stream);

    // 9. ff2 = ff1 @ lin2_w.T + b        (K = 2048)
    run_cvt(lin2_w, Wbf, (size_t)H * DFF, (size_t)H * DFF, stream);
    run_gemm(actB, Wbf, lin2_b, big_f, nullptr, NTOK, H, DFF, H, H, 0, stream);

    // 10. x3 = LN3(x2 + ff2) -> bf16 only
    add_ln<<<NTOK, 256, 0, stream>>>(x2_f, big_f, ln3_g, ln3_bb, nullptr, actA, 0);

    // 11. logits = x3 @ proj_w.T  (3072 x 51865) -- 8-phase kernel
    run_cvt(proj_w, Wbf, (size_t)V * H, (size_t)VPAD * H, stream);
    {
        dim3 grid((NTOK / 256) * (VPAD / 256));   // 12 * 203 = 2436
        gemm8p<<<grid, 512, 0, stream>>>(actA, Wbf, out, H, V, V, NTOK / 256);
    }
}

// Round 15
// 611.979 us; speedup vs baseline: 1.2338x; 1.2338x over previous
//
#include <hip/hip_runtime.h>

typedef __bf16 bf16;
typedef __bf16 bf16x4 __attribute__((ext_vector_type(4)));
typedef __bf16 bf16x8 __attribute__((ext_vector_type(8)));
typedef float f32x4 __attribute__((ext_vector_type(4)));

#define BM 128
#define BN 128
#define BK 32

// ---------------- async global->LDS (16B per lane) ----------------
__device__ __forceinline__ void async16(const void* g, void* l) {
    __builtin_amdgcn_global_load_lds(
        (__attribute__((address_space(1))) void*)g,
        (__attribute__((address_space(3))) void*)l,
        16, 0, 0);
}

// =============================================================================
// Proj GEMM (R10 schedule = session best): 256^2, BK=64, dbuf, 8 waves, deep
// load slack (stage A(k+1) then vmcnt(4) then barrier; ST_B before MFMAs),
// 2 barriers/K-tile. R15 change: epilogue stores CACHED (not NT).
// Evidence: R14 NT f32x4 -> WRITE 766 MB (1.2x amplification, odd-ldo 64B
// sector edges RMW at HBM); R4 cached f32x4 after LDS transpose -> WRITE
// 640 MB = exact output, FETCH unchanged ~250 MB. Schedule lessons: R5 (LDS
// traffic) null, R6-R8 (structures) regress, R10 (barrier thinning) null,
// R11 (32x32 MFMA) worse, R13/R14 (fine 8-phase) much worse.
// =============================================================================
__global__ __launch_bounds__(512, 2) void gemm8p(
    const bf16* __restrict__ A, const bf16* __restrict__ W,
    float* __restrict__ C, int K, int ldo, int Nstore, int nTilesM)
{
    __shared__ bf16 lds[2][32768];   // [dbuf][A 16384 | B 16384] = 128 KiB

    // bijective XCD swizzle (m204) + m-fastest ordering for W-panel L2 reuse
    int nwg = gridDim.x;
    int orig = blockIdx.x;
    int q = nwg >> 3, r = nwg & 7, xcd = orig & 7, local = orig >> 3;
    int wgid = (xcd < r ? xcd * (q + 1) : r * (q + 1) + (xcd - r) * q) + local;
    const int brow = (wgid % nTilesM) * 256;
    const int bcol = (wgid / nTilesM) * 256;

    const int t = threadIdx.x;
    const int wid = t >> 6, lane = t & 63;
    const int wm = wid >> 2, wn = wid & 3;
    const int l15 = lane & 15, l7 = lane & 7, lhi = lane >> 4;

    // staging source: 64-row units, 8 chunks/row, inverse-swizzled chunk
    const int lr = t >> 3;                 // 0..63
    const int cc = (t & 7) ^ (lr & 7);
    const bf16* gA = A + (size_t)(brow + lr) * K + cc * 8;
    const bf16* gW = W + (size_t)(bcol + lr) * K + cc * 8;
    const int dsto = wid * 512;            // wave-uniform LDS base (HW adds lane*16B)

    // fragment read constants (elements)
    const int kx0 = ((0 * 4 + lhi) ^ l7) * 8;
    const int kx1 = ((1 * 4 + lhi) ^ l7) * 8;
    const int abase = wm * 8192 + l15 * 64;
    const int bbase = 16384 + (wn >> 1) * 8192 + ((wn & 1) * 64 + l15) * 64;

    f32x4 acc[8][4] = {};
    const int nkt = K >> 6;                // 12 for K=768

    #define ST_A(dst, k0)                                             \
        async16(gA + (k0),                   (dst) + dsto);           \
        async16(gA + (size_t)64 * K + (k0),  (dst) + 4096 + dsto);    \
        async16(gA + (size_t)128 * K + (k0), (dst) + 8192 + dsto);    \
        async16(gA + (size_t)192 * K + (k0), (dst) + 12288 + dsto);
    #define ST_B(dst, k0)                                                     \
        async16(gW + (k0),                   (dst) + 16384 + dsto);           \
        async16(gW + (size_t)64 * K + (k0),  (dst) + 20480 + dsto);           \
        async16(gW + (size_t)128 * K + (k0), (dst) + 24576 + dsto);           \
        async16(gW + (size_t)192 * K + (k0), (dst) + 28672 + dsto);

    // prologue: stage tile 0 fully (8 loads)
    { ST_A(&lds[0][0], 0); ST_B(&lds[0][0], 0); }

    bf16x8 a[4][2], b[4][2];
    for (int kt = 0; kt < nkt; ++kt) {
        const bf16* cur = &lds[kt & 1][0];
        bf16* stg = &lds[(kt + 1) & 1][0];
        const int k1 = (kt + 1) << 6;
        const bool st = (kt + 1 < nkt);

        // ---- half 1: stage A(k+1); drain tile k; read A0+B; stage B(k+1);
        //      32 MFMA Q(0,*) ----
        if (st) { ST_A(stg, k1); }
        if (st) asm volatile("s_waitcnt vmcnt(4)" ::: "memory");
        else    asm volatile("s_waitcnt vmcnt(0)" ::: "memory");
        __builtin_amdgcn_s_barrier();
        #pragma unroll
        for (int fi = 0; fi < 4; fi++) {
            a[fi][0] = *(const bf16x8*)(cur + abase + fi * 1024 + kx0);
            a[fi][1] = *(const bf16x8*)(cur + abase + fi * 1024 + kx1);
        }
        #pragma unroll
        for (int fj = 0; fj < 4; fj++) {
            b[fj][0] = *(const bf16x8*)(cur + bbase + fj * 1024 + kx0);
            b[fj][1] = *(const bf16x8*)(cur + bbase + fj * 1024 + kx1);
        }
        if (st) { ST_B(stg, k1); }
        __builtin_amdgcn_s_setprio(1);
        #pragma unroll
        for (int fi = 0; fi < 4; fi++)
            #pragma unroll
            for (int fj = 0; fj < 4; fj++) {
                f32x4 c0 = acc[fi][fj];
                c0 = __builtin_amdgcn_mfma_f32_16x16x32_bf16(a[fi][0], b[fj][0], c0, 0,0,0);
                c0 = __builtin_amdgcn_mfma_f32_16x16x32_bf16(a[fi][1], b[fj][1], c0, 0,0,0);
                acc[fi][fj] = c0;
            }
        __builtin_amdgcn_s_setprio(0);

        // ---- half 2: read A1; 16 MFMA Q(1,0..1); barrier; 16 MFMA Q(1,2..3) --
        #pragma unroll
        for (int fi = 0; fi < 4; fi++) {
            a[fi][0] = *(const bf16x8*)(cur + abase + 4096 + fi * 1024 + kx0);
            a[fi][1] = *(const bf16x8*)(cur + abase + 4096 + fi * 1024 + kx1);
        }
        __builtin_amdgcn_s_setprio(1);
        #pragma unroll
        for (int fi = 0; fi < 4; fi++)
            #pragma unroll
            for (int fj = 0; fj < 2; fj++) {
                f32x4 c0 = acc[4 + fi][fj];
                c0 = __builtin_amdgcn_mfma_f32_16x16x32_bf16(a[fi][0], b[fj][0], c0, 0,0,0);
                c0 = __builtin_amdgcn_mfma_f32_16x16x32_bf16(a[fi][1], b[fj][1], c0, 0,0,0);
                acc[4 + fi][fj] = c0;
            }
        __builtin_amdgcn_s_setprio(0);
        __builtin_amdgcn_s_barrier();   // cur reads done; next ST_A may overwrite
        __builtin_amdgcn_s_setprio(1);
        #pragma unroll
        for (int fi = 0; fi < 4; fi++)
            #pragma unroll
            for (int fj = 2; fj < 4; fj++) {
                f32x4 c0 = acc[4 + fi][fj];
                c0 = __builtin_amdgcn_mfma_f32_16x16x32_bf16(a[fi][0], b[fj][0], c0, 0,0,0);
                c0 = __builtin_amdgcn_mfma_f32_16x16x32_bf16(a[fi][1], b[fj][1], c0, 0,0,0);
                acc[4 + fi][fj] = c0;
            }
        __builtin_amdgcn_s_setprio(0);
    }
    #undef ST_A
    #undef ST_B

    // ---- epilogue: LDS transpose (XOR swizzle) -> contiguous CACHED f32x4
    float* ldsf = (float*)&lds[0][0];
    const int lhi4 = lhi * 4;
    #pragma unroll
    for (int h = 0; h < 2; h++) {
        if (h) __builtin_amdgcn_s_barrier();  // h0 gather reads consumed
        #pragma unroll
        for (int fi4 = 0; fi4 < 4; fi4++) {
            #pragma unroll
            for (int fj = 0; fj < 4; fj++) {
                f32x4 v = acc[h * 4 + fi4][fj];
                int row0 = wm * 64 + fi4 * 16 + lhi4;
                int col = wn * 64 + fj * 16 + l15;
                #pragma unroll
                for (int r2 = 0; r2 < 4; r2++) {
                    int row = row0 + r2;
                    ldsf[row * 256 + (col ^ ((row & 12) << 1))] = v[r2];
                }
            }
        }
        __builtin_amdgcn_s_barrier();
        #pragma unroll
        for (int i = 0; i < 16; i++) {
            int c = i * 512 + t;               // 0..8191 chunks of 16B
            int row = c >> 6, ch = c & 63;
            f32x4 v = *(const f32x4*)(ldsf + row * 256
                                      + ((ch ^ ((row & 12) >> 1)) << 2));
            int grow = brow + (row >> 6) * 128 + h * 64 + (row & 63);
            int gcol = bcol + ch * 4;
            float* dst = C + (size_t)grow * ldo + gcol;
            if (gcol + 4 <= Nstore) {
                *(f32x4*)dst = v;              // cached: L2 write-combines
            } else {
                #pragma unroll
                for (int k2 = 0; k2 < 4; k2++)
                    if (gcol + k2 < Nstore) dst[k2] = v[k2];
            }
        }
    }
}

// ---------------- bf16 MFMA GEMM (128^2, m97 structure) for small GEMMs -----
__global__ __launch_bounds__(256) void gemm_bt(
    const bf16* __restrict__ A, const bf16* __restrict__ W,
    const float* __restrict__ bias,
    float* __restrict__ outF, bf16* __restrict__ outB,
    int M, int K, int ldo, int Nstore, int relu)
{
    __shared__ bf16 As[BM * BK];
    __shared__ bf16 Ws[BN * BK];
    const int brow = blockIdx.y * BM;
    const int bcol = blockIdx.x * BN;
    const int t = threadIdx.x;
    const int wv = t >> 6;
    const int lane = t & 63;
    const int wrow = (wv >> 1) * 64;
    const int wcol = (wv & 1) * 64;

    f32x4 acc[4][4] = {};

    const int row0 = t >> 2;
    const int cg = (t & 3) * 8;
    const bf16* gA = A + (size_t)(brow + row0) * K + cg;
    const bf16* gW = W + (size_t)(bcol + row0) * K + cg;
    const size_t rstep = (size_t)64 * K;
    bf16* lA0 = As + wv * 512;
    bf16* lA1 = As + 2048 + wv * 512;
    bf16* lW0 = Ws + wv * 512;
    bf16* lW1 = Ws + 2048 + wv * 512;

    const int lrow = lane & 15;
    const int kg = (lane >> 4) * 8;

    for (int k0 = 0; k0 < K; k0 += BK) {
        if (k0) __syncthreads();
        async16(gA + k0, lA0);
        async16(gA + rstep + k0, lA1);
        async16(gW + k0, lW0);
        async16(gW + rstep + k0, lW1);
        __syncthreads();
        bf16x8 af[4], wf[4];
        #pragma unroll
        for (int i = 0; i < 4; i++)
            af[i] = *(const bf16x8*)(As + (wrow + i * 16 + lrow) * BK + kg);
        #pragma unroll
        for (int j = 0; j < 4; j++)
            wf[j] = *(const bf16x8*)(Ws + (wcol + j * 16 + lrow) * BK + kg);
        #pragma unroll
        for (int i = 0; i < 4; i++)
            #pragma unroll
            for (int j = 0; j < 4; j++)
                acc[i][j] = __builtin_amdgcn_mfma_f32_16x16x32_bf16(
                    af[i], wf[j], acc[i][j], 0, 0, 0);
    }

    const int lcol = lane & 15;
    const int rb = (lane >> 4) * 4;
    #pragma unroll
    for (int j = 0; j < 4; j++) {
        int n = bcol + wcol + j * 16 + lcol;
        if (n >= Nstore) continue;
        float bv = bias ? bias[n] : 0.f;
        #pragma unroll
        for (int i = 0; i < 4; i++) {
            #pragma unroll
            for (int r = 0; r < 4; r++) {
                int m = brow + wrow + i * 16 + rb + r;
                float v = acc[i][j][r] + bv;
                if (relu) v = fmaxf(v, 0.f);
                size_t off = (size_t)m * ldo + n;
                if (outF) outF[off] = v;
                if (outB) outB[off] = (bf16)v;
            }
        }
    }
}

// ---------------- fp32 -> bf16 convert (zero-pads rows beyond nvalid) --------
// Non-temporal source reads: big weights (proj_w = 159MB) are read ONCE.
__global__ __launch_bounds__(256) void cvt_bf16(
    const float* __restrict__ in, bf16* __restrict__ out,
    size_t nvalid, size_t ntotal)
{
    size_t i = ((size_t)blockIdx.x * 256 + threadIdx.x) * 4;
    if (i >= ntotal) return;
    bf16x4 r;
    if (i < nvalid) {
        f32x4 f = __builtin_nontemporal_load((const f32x4*)(in + i));
        r[0] = (bf16)f[0]; r[1] = (bf16)f[1]; r[2] = (bf16)f[2]; r[3] = (bf16)f[3];
    } else {
        r[0] = (bf16)0.f; r[1] = (bf16)0.f; r[2] = (bf16)0.f; r[3] = (bf16)0.f;
    }
    *(bf16x4*)(out + i) = r;
}

// ---------------- build tgt = [start, emb[tok0], emb[tok1]] per sequence -----
__global__ __launch_bounds__(256) void build_tgt(
    const float* __restrict__ start, const float* __restrict__ emb,
    const int* __restrict__ toks, float* __restrict__ outF, bf16* __restrict__ outB)
{
    int r = blockIdx.x;               // 0..3071, r = n*3 + p
    int n = r / 3, p = r % 3;
    const float* src = (p == 0) ? start : emb + (size_t)toks[n * 3 + (p - 1)] * 768;
    int t = threadIdx.x;
    #pragma unroll
    for (int j = 0; j < 3; j++) {
        int c = t + j * 256;
        float v = src[c];
        outF[(size_t)r * 768 + c] = v;
        outB[(size_t)r * 768 + c] = (bf16)v;
    }
}

// ---------------- 3-token causal self-attention, one wave per (n,head) -------
__global__ __launch_bounds__(64) void attn3(
    const float* __restrict__ qkv, bf16* __restrict__ o)
{
    int blk = blockIdx.x;             // n*4 + h
    int n = blk >> 2, h = blk & 3;
    int lane = threadIdx.x;
    const float* base = qkv + (size_t)n * 3 * 2304 + h * 192;
    float q[3][3], k[3][3], v[3][3];
    #pragma unroll
    for (int p = 0; p < 3; p++)
        #pragma unroll
        for (int j = 0; j < 3; j++) {
            int d = lane + j * 64;
            q[p][j] = base[p * 2304 + d];
            k[p][j] = base[p * 2304 + 768 + d];
            v[p][j] = base[p * 2304 + 1536 + d];
        }
    float s[3][3];
    #pragma unroll
    for (int p = 0; p < 3; p++)
        #pragma unroll
        for (int pk = 0; pk < 3; pk++) {
            if (pk > p) continue;
            float ps = q[p][0] * k[pk][0] + q[p][1] * k[pk][1] + q[p][2] * k[pk][2];
            #pragma unroll
            for (int off = 32; off; off >>= 1) ps += __shfl_xor(ps, off);
            s[p][pk] = ps * 0.072168783648703220563f;   // 1/sqrt(192)
        }
    float a[3][3] = {};
    a[0][0] = 1.f;
    {
        float m = fmaxf(s[1][0], s[1][1]);
        float e0 = expf(s[1][0] - m), e1 = expf(s[1][1] - m);
        float inv = 1.f / (e0 + e1);
        a[1][0] = e0 * inv; a[1][1] = e1 * inv;
    }
    {
        float m = fmaxf(fmaxf(s[2][0], s[2][1]), s[2][2]);
        float e0 = expf(s[2][0] - m), e1 = expf(s[2][1] - m), e2 = expf(s[2][2] - m);
        float inv = 1.f / (e0 + e1 + e2);
        a[2][0] = e0 * inv; a[2][1] = e1 * inv; a[2][2] = e2 * inv;
    }
    bf16* ob = o + (size_t)n * 3 * 768 + h * 192;
    #pragma unroll
    for (int p = 0; p < 3; p++)
        #pragma unroll
        for (int j = 0; j < 3; j++) {
            float val = a[p][0] * v[0][j];
            if (p >= 1) val += a[p][1] * v[1][j];
            if (p >= 2) val += a[p][2] * v[2][j];
            ob[p * 768 + lane + j * 64] = (bf16)val;
        }
}

// ---------------- x = LN(a + b) ; b optionally broadcast over 3 positions ----
__global__ __launch_bounds__(256) void add_ln(
    const float* __restrict__ a, const float* __restrict__ b,
    const float* __restrict__ g, const float* __restrict__ be,
    float* __restrict__ outF, bf16* __restrict__ outB, int bcast)
{
    int r = blockIdx.x;
    int t = threadIdx.x;
    const float* ar = a + (size_t)r * 768;
    const float* br = b + (size_t)(bcast ? (r / 3) : r) * 768;
    float x[3];
    float s = 0.f, sq = 0.f;
    #pragma unroll
    for (int j = 0; j < 3; j++) {
        int c = t + j * 256;
        x[j] = ar[c] + br[c];
        s += x[j]; sq += x[j] * x[j];
    }
    #pragma unroll
    for (int off = 32; off; off >>= 1) {
        s += __shfl_xor(s, off);
        sq += __shfl_xor(sq, off);
    }
    __shared__ float ls[4], lq[4];
    int wv = t >> 6;
    if ((t & 63) == 0) { ls[wv] = s; lq[wv] = sq; }
    __syncthreads();
    s = ls[0] + ls[1] + ls[2] + ls[3];
    sq = lq[0] + lq[1] + lq[2] + lq[3];
    float mean = s * (1.f / 768.f);
    float var = sq * (1.f / 768.f) - mean * mean;
    float inv = rsqrtf(var + 1e-5f);
    #pragma unroll
    for (int j = 0; j < 3; j++) {
        int c = t + j * 256;
        float y = (x[j] - mean) * inv * g[c] + be[c];
        if (outF) outF[(size_t)r * 768 + c] = y;
        if (outB) outB[(size_t)r * 768 + c] = (bf16)y;
    }
}

// =============================================================================
static inline void run_gemm(const bf16* A, const bf16* W, const float* bias,
                            float* outF, bf16* outB, int M, int Npad, int K,
                            int ldo, int Nstore, int relu, hipStream_t s)
{
    dim3 grid(Npad / BN, M / BM);
    gemm_bt<<<grid, 256, 0, s>>>(A, W, bias, outF, outB, M, K, ldo, Nstore, relu);
}

static inline void run_cvt(const float* in, bf16* out, size_t nvalid,
                           size_t ntotal, hipStream_t s)
{
    int blocks = (int)((ntotal / 4 + 255) / 256);
    cvt_bf16<<<blocks, 256, 0, s>>>(in, out, nvalid, ntotal);
}

extern "C" void kernel_launch(void* const* d_in, const int* in_sizes, int n_in,
                              void* d_out, int out_size, void* d_ws, size_t ws_size,
                              hipStream_t stream)
{
    const float* enc      = (const float*)d_in[0];   // (1024, 768)
    const int*   toks     = (const int*)d_in[1];     // (1024, 3)
    const float* start    = (const float*)d_in[2];   // (1, 768)
    const float* emb      = (const float*)d_in[3];   // (51865, 768)
    const float* sa_in_w  = (const float*)d_in[4];   // (2304, 768)
    const float* sa_in_b  = (const float*)d_in[5];
    const float* sa_out_w = (const float*)d_in[6];   // (768, 768)
    const float* sa_out_b = (const float*)d_in[7];
    const float* ca_in_w  = (const float*)d_in[8];   // (2304, 768); only Wv used
    const float* ca_in_b  = (const float*)d_in[9];
    const float* ca_out_w = (const float*)d_in[10];  // (768, 768)
    const float* ca_out_b = (const float*)d_in[11];
    const float* lin1_w   = (const float*)d_in[12];  // (2048, 768)
    const float* lin1_b   = (const float*)d_in[13];
    const float* lin2_w   = (const float*)d_in[14];  // (768, 2048)
    const float* lin2_b   = (const float*)d_in[15];
    const float* ln1_g    = (const float*)d_in[16];
    const float* ln1_bb   = (const float*)d_in[17];
    const float* ln2_g    = (const float*)d_in[18];
    const float* ln2_bb   = (const float*)d_in[19];
    const float* ln3_g    = (const float*)d_in[20];
    const float* ln3_bb   = (const float*)d_in[21];
    const float* proj_w   = (const float*)d_in[22];  // (51865, 768)
    float* out = (float*)d_out;

    const int NTOK = 3072;          // B*T*NT
    const int NM   = 1024;          // B*T
    const int H    = 768;
    const int V    = 51865;
    const int VPAD = 51968;         // 203*256
    const int DFF  = 2048;

    char* p = (char*)d_ws;
    auto alloc = [&](size_t bytes) {
        void* r = (void*)p;
        p += (bytes + 255) & ~(size_t)255;
        return r;
    };
    float* tgt_f = (float*)alloc((size_t)NTOK * H * 4);
    float* x1_f  = (float*)alloc((size_t)NTOK * H * 4);
    float* x2_f  = (float*)alloc((size_t)NTOK * H * 4);
    float* big_f = (float*)alloc((size_t)NTOK * 2304 * 4);  // qkv / gemm fp32 outs
    bf16*  actA  = (bf16*)alloc((size_t)NTOK * 2304 * 2);   // bf16 activations A
    bf16*  actB  = (bf16*)alloc((size_t)NTOK * DFF * 2);    // bf16 activations B
    bf16*  Wbf   = (bf16*)alloc((size_t)VPAD * H * 2);      // bf16 weights (reused)
    bf16*  mem_bf = actB;                                   // (1024,768) carved
    bf16*  v_bf   = actB + (size_t)NM * H;                  // (1024,768) carved
    float* cao_f  = big_f + (size_t)NTOK * H;               // (1024,768) carved

    // 1. tgt = [start, emb[t0], emb[t1]]
    build_tgt<<<NTOK, 256, 0, stream>>>(start, emb, toks, tgt_f, actA);

    // 2. qkv = tgt @ sa_in_w.T + b       (3072 x 2304)
    run_cvt(sa_in_w, Wbf, (size_t)2304 * H, (size_t)2304 * H, stream);
    run_gemm(actA, Wbf, sa_in_b, big_f, nullptr, NTOK, 2304, H, 2304, 2304, 0, stream);

    // 3. 3x3 causal attention -> o (bf16)
    attn3<<<NM * 4, 64, 0, stream>>>(big_f, actA);

    // 4. sa = o @ sa_out_w.T + b
    run_cvt(sa_out_w, Wbf, (size_t)H * H, (size_t)H * H, stream);
    run_gemm(actA, Wbf, sa_out_b, big_f, nullptr, NTOK, H, H, H, H, 0, stream);

    // 5. x1 = LN1(tgt + sa)
    add_ln<<<NTOK, 256, 0, stream>>>(tgt_f, big_f, ln1_g, ln1_bb, x1_f, nullptr, 0);

    // 6. cross-attn (Lk=1 => softmax==1 => output == V projection of memory)
    run_cvt(enc, mem_bf, (size_t)NM * H, (size_t)NM * H, stream);
    run_cvt(ca_in_w + (size_t)1536 * H, Wbf, (size_t)H * H, (size_t)H * H, stream);
    run_gemm(mem_bf, Wbf, ca_in_b + 1536, nullptr, v_bf, NM, H, H, H, H, 0, stream);
    run_cvt(ca_out_w, Wbf, (size_t)H * H, (size_t)H * H, stream);
    run_gemm(v_bf, Wbf, ca_out_b, cao_f, nullptr, NM, H, H, H, H, 0, stream);

    // 7. x2 = LN2(x1 + ca_out[broadcast])
    add_ln<<<NTOK, 256, 0, stream>>>(x1_f, cao_f, ln2_g, ln2_bb, x2_f, actA, 1);

    // 8. ff1 = relu(x2 @ lin1_w.T + b)   (bf16 only)
    run_cvt(lin1_w, Wbf, (size_t)DFF * H, (size_t)DFF * H, stream);
    run_gemm(actA, Wbf, lin1_b, nullptr, actB, NTOK, DFF, H, DFF, DFF, 1, stream);

    // 9. ff2 = ff1 @ lin2_w.T + b        (K = 2048)
    run_cvt(lin2_w, Wbf, (size_t)H * DFF, (size_t)H * DFF, stream);
    run_gemm(actB, Wbf, lin2_b, big_f, nullptr, NTOK, H, DFF, H, H, 0, stream);

    // 10. x3 = LN3(x2 + ff2) -> bf16 only
    add_ln<<<NTOK, 256, 0, stream>>>(x2_f, big_f, ln3_g, ln3_bb, nullptr, actA, 0);

    // 11. logits = x3 @ proj_w.T  (3072 x 51865) -- deep-slack 2-barrier kernel
    run_cvt(proj_w, Wbf, (size_t)V * H, (size_t)VPAD * H, stream);
    {
        dim3 grid((NTOK / 256) * (VPAD / 256));   // 12 * 203 = 2436
        gemm8p<<<grid, 512, 0, stream>>>(actA, Wbf, out, H, V, V, NTOK / 256);
    }
}

// Round 16
// 545.759 us; speedup vs baseline: 1.3835x; 1.1213x over previous
//
#include <hip/hip_runtime.h>

typedef __bf16 bf16;
typedef __bf16 bf16x4 __attribute__((ext_vector_type(4)));
typedef __bf16 bf16x8 __attribute__((ext_vector_type(8)));
typedef float f32x4 __attribute__((ext_vector_type(4)));

#define BM 128
#define BN 128
#define BK 32

// ---------------- async global->LDS (16B per lane) ----------------
__device__ __forceinline__ void async16(const void* g, void* l) {
    __builtin_amdgcn_global_load_lds(
        (__attribute__((address_space(1))) void*)g,
        (__attribute__((address_space(3))) void*)l,
        16, 0, 0);
}

// =============================================================================
// Proj GEMM (R10 = session best, restored verbatim): 256^2, BK=64, dbuf,
// 8 waves, deep load slack, 2 barriers/K-tile, LDS-transpose + NT contiguous
// f32x4 stores. R15 lesson: NT is load-bearing — cached stores write fewer
// bytes (639 vs 766 MB) but run at 2.4 vs 3.2 TB/s effective (write-allocate
// + writeback path slower than NT direct-to-HBM). Full search record:
// R5 LDS-traffic null; R6/R7/R8 structure swaps regress; R10 barrier-thin
// null; R11 32x32 worse; R13/R14 fine 8-phase much worse; R15 cached -12%.
// =============================================================================
__global__ __launch_bounds__(512, 2) void gemm8p(
    const bf16* __restrict__ A, const bf16* __restrict__ W,
    float* __restrict__ C, int K, int ldo, int Nstore, int nTilesM)
{
    __shared__ bf16 lds[2][32768];   // [dbuf][A 16384 | B 16384] = 128 KiB

    // bijective XCD swizzle (m204) + m-fastest ordering for W-panel L2 reuse
    int nwg = gridDim.x;
    int orig = blockIdx.x;
    int q = nwg >> 3, r = nwg & 7, xcd = orig & 7, local = orig >> 3;
    int wgid = (xcd < r ? xcd * (q + 1) : r * (q + 1) + (xcd - r) * q) + local;
    const int brow = (wgid % nTilesM) * 256;
    const int bcol = (wgid / nTilesM) * 256;

    const int t = threadIdx.x;
    const int wid = t >> 6, lane = t & 63;
    const int wm = wid >> 2, wn = wid & 3;
    const int l15 = lane & 15, l7 = lane & 7, lhi = lane >> 4;

    // staging source: 64-row units, 8 chunks/row, inverse-swizzled chunk
    const int lr = t >> 3;                 // 0..63
    const int cc = (t & 7) ^ (lr & 7);
    const bf16* gA = A + (size_t)(brow + lr) * K + cc * 8;
    const bf16* gW = W + (size_t)(bcol + lr) * K + cc * 8;
    const int dsto = wid * 512;            // wave-uniform LDS base (HW adds lane*16B)

    // fragment read constants (elements)
    const int kx0 = ((0 * 4 + lhi) ^ l7) * 8;
    const int kx1 = ((1 * 4 + lhi) ^ l7) * 8;
    const int abase = wm * 8192 + l15 * 64;
    const int bbase = 16384 + (wn >> 1) * 8192 + ((wn & 1) * 64 + l15) * 64;

    f32x4 acc[8][4] = {};
    const int nkt = K >> 6;                // 12 for K=768

    #define ST_A(dst, k0)                                             \
        async16(gA + (k0),                   (dst) + dsto);           \
        async16(gA + (size_t)64 * K + (k0),  (dst) + 4096 + dsto);    \
        async16(gA + (size_t)128 * K + (k0), (dst) + 8192 + dsto);    \
        async16(gA + (size_t)192 * K + (k0), (dst) + 12288 + dsto);
    #define ST_B(dst, k0)                                                     \
        async16(gW + (k0),                   (dst) + 16384 + dsto);           \
        async16(gW + (size_t)64 * K + (k0),  (dst) + 20480 + dsto);           \
        async16(gW + (size_t)128 * K + (k0), (dst) + 24576 + dsto);           \
        async16(gW + (size_t)192 * K + (k0), (dst) + 28672 + dsto);

    // prologue: stage tile 0 fully (8 loads)
    { ST_A(&lds[0][0], 0); ST_B(&lds[0][0], 0); }

    bf16x8 a[4][2], b[4][2];
    for (int kt = 0; kt < nkt; ++kt) {
        const bf16* cur = &lds[kt & 1][0];
        bf16* stg = &lds[(kt + 1) & 1][0];
        const int k1 = (kt + 1) << 6;
        const bool st = (kt + 1 < nkt);

        // ---- half 1: stage A(k+1); drain tile k; read A0+B; stage B(k+1);
        //      32 MFMA Q(0,*) ----
        if (st) { ST_A(stg, k1); }
        if (st) asm volatile("s_waitcnt vmcnt(4)" ::: "memory");
        else    asm volatile("s_waitcnt vmcnt(0)" ::: "memory");
        __builtin_amdgcn_s_barrier();
        #pragma unroll
        for (int fi = 0; fi < 4; fi++) {
            a[fi][0] = *(const bf16x8*)(cur + abase + fi * 1024 + kx0);
            a[fi][1] = *(const bf16x8*)(cur + abase + fi * 1024 + kx1);
        }
        #pragma unroll
        for (int fj = 0; fj < 4; fj++) {
            b[fj][0] = *(const bf16x8*)(cur + bbase + fj * 1024 + kx0);
            b[fj][1] = *(const bf16x8*)(cur + bbase + fj * 1024 + kx1);
        }
        if (st) { ST_B(stg, k1); }
        __builtin_amdgcn_s_setprio(1);
        #pragma unroll
        for (int fi = 0; fi < 4; fi++)
            #pragma unroll
            for (int fj = 0; fj < 4; fj++) {
                f32x4 c0 = acc[fi][fj];
                c0 = __builtin_amdgcn_mfma_f32_16x16x32_bf16(a[fi][0], b[fj][0], c0, 0,0,0);
                c0 = __builtin_amdgcn_mfma_f32_16x16x32_bf16(a[fi][1], b[fj][1], c0, 0,0,0);
                acc[fi][fj] = c0;
            }
        __builtin_amdgcn_s_setprio(0);

        // ---- half 2: read A1; 16 MFMA Q(1,0..1); barrier; 16 MFMA Q(1,2..3) --
        #pragma unroll
        for (int fi = 0; fi < 4; fi++) {
            a[fi][0] = *(const bf16x8*)(cur + abase + 4096 + fi * 1024 + kx0);
            a[fi][1] = *(const bf16x8*)(cur + abase + 4096 + fi * 1024 + kx1);
        }
        __builtin_amdgcn_s_setprio(1);
        #pragma unroll
        for (int fi = 0; fi < 4; fi++)
            #pragma unroll
            for (int fj = 0; fj < 2; fj++) {
                f32x4 c0 = acc[4 + fi][fj];
                c0 = __builtin_amdgcn_mfma_f32_16x16x32_bf16(a[fi][0], b[fj][0], c0, 0,0,0);
                c0 = __builtin_amdgcn_mfma_f32_16x16x32_bf16(a[fi][1], b[fj][1], c0, 0,0,0);
                acc[4 + fi][fj] = c0;
            }
        __builtin_amdgcn_s_setprio(0);
        __builtin_amdgcn_s_barrier();   // cur reads done; next ST_A may overwrite
        __builtin_amdgcn_s_setprio(1);
        #pragma unroll
        for (int fi = 0; fi < 4; fi++)
            #pragma unroll
            for (int fj = 2; fj < 4; fj++) {
                f32x4 c0 = acc[4 + fi][fj];
                c0 = __builtin_amdgcn_mfma_f32_16x16x32_bf16(a[fi][0], b[fj][0], c0, 0,0,0);
                c0 = __builtin_amdgcn_mfma_f32_16x16x32_bf16(a[fi][1], b[fj][1], c0, 0,0,0);
                acc[4 + fi][fj] = c0;
            }
        __builtin_amdgcn_s_setprio(0);
    }
    #undef ST_A
    #undef ST_B

    // ---- epilogue: LDS transpose (XOR swizzle) -> contiguous NT f32x4 stores
    float* ldsf = (float*)&lds[0][0];
    const int lhi4 = lhi * 4;
    #pragma unroll
    for (int h = 0; h < 2; h++) {
        if (h) __builtin_amdgcn_s_barrier();  // h0 gather reads consumed
        #pragma unroll
        for (int fi4 = 0; fi4 < 4; fi4++) {
            #pragma unroll
            for (int fj = 0; fj < 4; fj++) {
                f32x4 v = acc[h * 4 + fi4][fj];
                int row0 = wm * 64 + fi4 * 16 + lhi4;
                int col = wn * 64 + fj * 16 + l15;
                #pragma unroll
                for (int r2 = 0; r2 < 4; r2++) {
                    int row = row0 + r2;
                    ldsf[row * 256 + (col ^ ((row & 12) << 1))] = v[r2];
                }
            }
        }
        __builtin_amdgcn_s_barrier();
        #pragma unroll
        for (int i = 0; i < 16; i++) {
            int c = i * 512 + t;               // 0..8191 chunks of 16B
            int row = c >> 6, ch = c & 63;
            f32x4 v = *(const f32x4*)(ldsf + row * 256
                                      + ((ch ^ ((row & 12) >> 1)) << 2));
            int grow = brow + (row >> 6) * 128 + h * 64 + (row & 63);
            int gcol = bcol + ch * 4;
            float* dst = C + (size_t)grow * ldo + gcol;
            if (gcol + 4 <= Nstore) {
                __builtin_nontemporal_store(v, (f32x4*)dst);
            } else {
                #pragma unroll
                for (int k2 = 0; k2 < 4; k2++)
                    if (gcol + k2 < Nstore) dst[k2] = v[k2];
            }
        }
    }
}

// ---------------- bf16 MFMA GEMM (128^2, m97 structure) for small GEMMs -----
__global__ __launch_bounds__(256) void gemm_bt(
    const bf16* __restrict__ A, const bf16* __restrict__ W,
    const float* __restrict__ bias,
    float* __restrict__ outF, bf16* __restrict__ outB,
    int M, int K, int ldo, int Nstore, int relu)
{
    __shared__ bf16 As[BM * BK];
    __shared__ bf16 Ws[BN * BK];
    const int brow = blockIdx.y * BM;
    const int bcol = blockIdx.x * BN;
    const int t = threadIdx.x;
    const int wv = t >> 6;
    const int lane = t & 63;
    const int wrow = (wv >> 1) * 64;
    const int wcol = (wv & 1) * 64;

    f32x4 acc[4][4] = {};

    const int row0 = t >> 2;
    const int cg = (t & 3) * 8;
    const bf16* gA = A + (size_t)(brow + row0) * K + cg;
    const bf16* gW = W + (size_t)(bcol + row0) * K + cg;
    const size_t rstep = (size_t)64 * K;
    bf16* lA0 = As + wv * 512;
    bf16* lA1 = As + 2048 + wv * 512;
    bf16* lW0 = Ws + wv * 512;
    bf16* lW1 = Ws + 2048 + wv * 512;

    const int lrow = lane & 15;
    const int kg = (lane >> 4) * 8;

    for (int k0 = 0; k0 < K; k0 += BK) {
        if (k0) __syncthreads();
        async16(gA + k0, lA0);
        async16(gA + rstep + k0, lA1);
        async16(gW + k0, lW0);
        async16(gW + rstep + k0, lW1);
        __syncthreads();
        bf16x8 af[4], wf[4];
        #pragma unroll
        for (int i = 0; i < 4; i++)
            af[i] = *(const bf16x8*)(As + (wrow + i * 16 + lrow) * BK + kg);
        #pragma unroll
        for (int j = 0; j < 4; j++)
            wf[j] = *(const bf16x8*)(Ws + (wcol + j * 16 + lrow) * BK + kg);
        #pragma unroll
        for (int i = 0; i < 4; i++)
            #pragma unroll
            for (int j = 0; j < 4; j++)
                acc[i][j] = __builtin_amdgcn_mfma_f32_16x16x32_bf16(
                    af[i], wf[j], acc[i][j], 0, 0, 0);
    }

    const int lcol = lane & 15;
    const int rb = (lane >> 4) * 4;
    #pragma unroll
    for (int j = 0; j < 4; j++) {
        int n = bcol + wcol + j * 16 + lcol;
        if (n >= Nstore) continue;
        float bv = bias ? bias[n] : 0.f;
        #pragma unroll
        for (int i = 0; i < 4; i++) {
            #pragma unroll
            for (int r = 0; r < 4; r++) {
                int m = brow + wrow + i * 16 + rb + r;
                float v = acc[i][j][r] + bv;
                if (relu) v = fmaxf(v, 0.f);
                size_t off = (size_t)m * ldo + n;
                if (outF) outF[off] = v;
                if (outB) outB[off] = (bf16)v;
            }
        }
    }
}

// ---------------- fp32 -> bf16 convert (zero-pads rows beyond nvalid) --------
// Non-temporal source reads: big weights (proj_w = 159MB) are read ONCE.
__global__ __launch_bounds__(256) void cvt_bf16(
    const float* __restrict__ in, bf16* __restrict__ out,
    size_t nvalid, size_t ntotal)
{
    size_t i = ((size_t)blockIdx.x * 256 + threadIdx.x) * 4;
    if (i >= ntotal) return;
    bf16x4 r;
    if (i < nvalid) {
        f32x4 f = __builtin_nontemporal_load((const f32x4*)(in + i));
        r[0] = (bf16)f[0]; r[1] = (bf16)f[1]; r[2] = (bf16)f[2]; r[3] = (bf16)f[3];
    } else {
        r[0] = (bf16)0.f; r[1] = (bf16)0.f; r[2] = (bf16)0.f; r[3] = (bf16)0.f;
    }
    *(bf16x4*)(out + i) = r;
}

// ---------------- build tgt = [start, emb[tok0], emb[tok1]] per sequence -----
__global__ __launch_bounds__(256) void build_tgt(
    const float* __restrict__ start, const float* __restrict__ emb,
    const int* __restrict__ toks, float* __restrict__ outF, bf16* __restrict__ outB)
{
    int r = blockIdx.x;               // 0..3071, r = n*3 + p
    int n = r / 3, p = r % 3;
    const float* src = (p == 0) ? start : emb + (size_t)toks[n * 3 + (p - 1)] * 768;
    int t = threadIdx.x;
    #pragma unroll
    for (int j = 0; j < 3; j++) {
        int c = t + j * 256;
        float v = src[c];
        outF[(size_t)r * 768 + c] = v;
        outB[(size_t)r * 768 + c] = (bf16)v;
    }
}

// ---------------- 3-token causal self-attention, one wave per (n,head) -------
__global__ __launch_bounds__(64) void attn3(
    const float* __restrict__ qkv, bf16* __restrict__ o)
{
    int blk = blockIdx.x;             // n*4 + h
    int n = blk >> 2, h = blk & 3;
    int lane = threadIdx.x;
    const float* base = qkv + (size_t)n * 3 * 2304 + h * 192;
    float q[3][3], k[3][3], v[3][3];
    #pragma unroll
    for (int p = 0; p < 3; p++)
        #pragma unroll
        for (int j = 0; j < 3; j++) {
            int d = lane + j * 64;
            q[p][j] = base[p * 2304 + d];
            k[p][j] = base[p * 2304 + 768 + d];
            v[p][j] = base[p * 2304 + 1536 + d];
        }
    float s[3][3];
    #pragma unroll
    for (int p = 0; p < 3; p++)
        #pragma unroll
        for (int pk = 0; pk < 3; pk++) {
            if (pk > p) continue;
            float ps = q[p][0] * k[pk][0] + q[p][1] * k[pk][1] + q[p][2] * k[pk][2];
            #pragma unroll
            for (int off = 32; off; off >>= 1) ps += __shfl_xor(ps, off);
            s[p][pk] = ps * 0.072168783648703220563f;   // 1/sqrt(192)
        }
    float a[3][3] = {};
    a[0][0] = 1.f;
    {
        float m = fmaxf(s[1][0], s[1][1]);
        float e0 = expf(s[1][0] - m), e1 = expf(s[1][1] - m);
        float inv = 1.f / (e0 + e1);
        a[1][0] = e0 * inv; a[1][1] = e1 * inv;
    }
    {
        float m = fmaxf(fmaxf(s[2][0], s[2][1]), s[2][2]);
        float e0 = expf(s[2][0] - m), e1 = expf(s[2][1] - m), e2 = expf(s[2][2] - m);
        float inv = 1.f / (e0 + e1 + e2);
        a[2][0] = e0 * inv; a[2][1] = e1 * inv; a[2][2] = e2 * inv;
    }
    bf16* ob = o + (size_t)n * 3 * 768 + h * 192;
    #pragma unroll
    for (int p = 0; p < 3; p++)
        #pragma unroll
        for (int j = 0; j < 3; j++) {
            float val = a[p][0] * v[0][j];
            if (p >= 1) val += a[p][1] * v[1][j];
            if (p >= 2) val += a[p][2] * v[2][j];
            ob[p * 768 + lane + j * 64] = (bf16)val;
        }
}

// ---------------- x = LN(a + b) ; b optionally broadcast over 3 positions ----
__global__ __launch_bounds__(256) void add_ln(
    const float* __restrict__ a, const float* __restrict__ b,
    const float* __restrict__ g, const float* __restrict__ be,
    float* __restrict__ outF, bf16* __restrict__ outB, int bcast)
{
    int r = blockIdx.x;
    int t = threadIdx.x;
    const float* ar = a + (size_t)r * 768;
    const float* br = b + (size_t)(bcast ? (r / 3) : r) * 768;
    float x[3];
    float s = 0.f, sq = 0.f;
    #pragma unroll
    for (int j = 0; j < 3; j++) {
        int c = t + j * 256;
        x[j] = ar[c] + br[c];
        s += x[j]; sq += x[j] * x[j];
    }
    #pragma unroll
    for (int off = 32; off; off >>= 1) {
        s += __shfl_xor(s, off);
        sq += __shfl_xor(sq, off);
    }
    __shared__ float ls[4], lq[4];
    int wv = t >> 6;
    if ((t & 63) == 0) { ls[wv] = s; lq[wv] = sq; }
    __syncthreads();
    s = ls[0] + ls[1] + ls[2] + ls[3];
    sq = lq[0] + lq[1] + lq[2] + lq[3];
    float mean = s * (1.f / 768.f);
    float var = sq * (1.f / 768.f) - mean * mean;
    float inv = rsqrtf(var + 1e-5f);
    #pragma unroll
    for (int j = 0; j < 3; j++) {
        int c = t + j * 256;
        float y = (x[j] - mean) * inv * g[c] + be[c];
        if (outF) outF[(size_t)r * 768 + c] = y;
        if (outB) outB[(size_t)r * 768 + c] = (bf16)y;
    }
}

// =============================================================================
static inline void run_gemm(const bf16* A, const bf16* W, const float* bias,
                            float* outF, bf16* outB, int M, int Npad, int K,
                            int ldo, int Nstore, int relu, hipStream_t s)
{
    dim3 grid(Npad / BN, M / BM);
    gemm_bt<<<grid, 256, 0, s>>>(A, W, bias, outF, outB, M, K, ldo, Nstore, relu);
}

static inline void run_cvt(const float* in, bf16* out, size_t nvalid,
                           size_t ntotal, hipStream_t s)
{
    int blocks = (int)((ntotal / 4 + 255) / 256);
    cvt_bf16<<<blocks, 256, 0, s>>>(in, out, nvalid, ntotal);
}

extern "C" void kernel_launch(void* const* d_in, const int* in_sizes, int n_in,
                              void* d_out, int out_size, void* d_ws, size_t ws_size,
                              hipStream_t stream)
{
    const float* enc      = (const float*)d_in[0];   // (1024, 768)
    const int*   toks     = (const int*)d_in[1];     // (1024, 3)
    const float* start    = (const float*)d_in[2];   // (1, 768)
    const float* emb      = (const float*)d_in[3];   // (51865, 768)
    const float* sa_in_w  = (const float*)d_in[4];   // (2304, 768)
    const float* sa_in_b  = (const float*)d_in[5];
    const float* sa_out_w = (const float*)d_in[6];   // (768, 768)
    const float* sa_out_b = (const float*)d_in[7];
    const float* ca_in_w  = (const float*)d_in[8];   // (2304, 768); only Wv used
    const float* ca_in_b  = (const float*)d_in[9];
    const float* ca_out_w = (const float*)d_in[10];  // (768, 768)
    const float* ca_out_b = (const float*)d_in[11];
    const float* lin1_w   = (const float*)d_in[12];  // (2048, 768)
    const float* lin1_b   = (const float*)d_in[13];
    const float* lin2_w   = (const float*)d_in[14];  // (768, 2048)
    const float* lin2_b   = (const float*)d_in[15];
    const float* ln1_g    = (const float*)d_in[16];
    const float* ln1_bb   = (const float*)d_in[17];
    const float* ln2_g    = (const float*)d_in[18];
    const float* ln2_bb   = (const float*)d_in[19];
    const float* ln3_g    = (const float*)d_in[20];
    const float* ln3_bb   = (const float*)d_in[21];
    const float* proj_w   = (const float*)d_in[22];  // (51865, 768)
    float* out = (float*)d_out;

    const int NTOK = 3072;          // B*T*NT
    const int NM   = 1024;          // B*T
    const int H    = 768;
    const int V    = 51865;
    const int VPAD = 51968;         // 203*256
    const int DFF  = 2048;

    char* p = (char*)d_ws;
    auto alloc = [&](size_t bytes) {
        void* r = (void*)p;
        p += (bytes + 255) & ~(size_t)255;
        return r;
    };
    float* tgt_f = (float*)alloc((size_t)NTOK * H * 4);
    float* x1_f  = (float*)alloc((size_t)NTOK * H * 4);
    float* x2_f  = (float*)alloc((size_t)NTOK * H * 4);
    float* big_f = (float*)alloc((size_t)NTOK * 2304 * 4);  // qkv / gemm fp32 outs
    bf16*  actA  = (bf16*)alloc((size_t)NTOK * 2304 * 2);   // bf16 activations A
    bf16*  actB  = (bf16*)alloc((size_t)NTOK * DFF * 2);    // bf16 activations B
    bf16*  Wbf   = (bf16*)alloc((size_t)VPAD * H * 2);      // bf16 weights (reused)
    bf16*  mem_bf = actB;                                   // (1024,768) carved
    bf16*  v_bf   = actB + (size_t)NM * H;                  // (1024,768) carved
    float* cao_f  = big_f + (size_t)NTOK * H;               // (1024,768) carved

    // 1. tgt = [start, emb[t0], emb[t1]]
    build_tgt<<<NTOK, 256, 0, stream>>>(start, emb, toks, tgt_f, actA);

    // 2. qkv = tgt @ sa_in_w.T + b       (3072 x 2304)
    run_cvt(sa_in_w, Wbf, (size_t)2304 * H, (size_t)2304 * H, stream);
    run_gemm(actA, Wbf, sa_in_b, big_f, nullptr, NTOK, 2304, H, 2304, 2304, 0, stream);

    // 3. 3x3 causal attention -> o (bf16)
    attn3<<<NM * 4, 64, 0, stream>>>(big_f, actA);

    // 4. sa = o @ sa_out_w.T + b
    run_cvt(sa_out_w, Wbf, (size_t)H * H, (size_t)H * H, stream);
    run_gemm(actA, Wbf, sa_out_b, big_f, nullptr, NTOK, H, H, H, H, 0, stream);

    // 5. x1 = LN1(tgt + sa)
    add_ln<<<NTOK, 256, 0, stream>>>(tgt_f, big_f, ln1_g, ln1_bb, x1_f, nullptr, 0);

    // 6. cross-attn (Lk=1 => softmax==1 => output == V projection of memory)
    run_cvt(enc, mem_bf, (size_t)NM * H, (size_t)NM * H, stream);
    run_cvt(ca_in_w + (size_t)1536 * H, Wbf, (size_t)H * H, (size_t)H * H, stream);
    run_gemm(mem_bf, Wbf, ca_in_b + 1536, nullptr, v_bf, NM, H, H, H, H, 0, stream);
    run_cvt(ca_out_w, Wbf, (size_t)H * H, (size_t)H * H, stream);
    run_gemm(v_bf, Wbf, ca_out_b, cao_f, nullptr, NM, H, H, H, H, 0, stream);

    // 7. x2 = LN2(x1 + ca_out[broadcast])
    add_ln<<<NTOK, 256, 0, stream>>>(x1_f, cao_f, ln2_g, ln2_bb, x2_f, actA, 1);

    // 8. ff1 = relu(x2 @ lin1_w.T + b)   (bf16 only)
    run_cvt(lin1_w, Wbf, (size_t)DFF * H, (size_t)DFF * H, stream);
    run_gemm(actA, Wbf, lin1_b, nullptr, actB, NTOK, DFF, H, DFF, DFF, 1, stream);

    // 9. ff2 = ff1 @ lin2_w.T + b        (K = 2048)
    run_cvt(lin2_w, Wbf, (size_t)H * DFF, (size_t)H * DFF, stream);
    run_gemm(actB, Wbf, lin2_b, big_f, nullptr, NTOK, H, DFF, H, H, 0, stream);

    // 10. x3 = LN3(x2 + ff2) -> bf16 only
    add_ln<<<NTOK, 256, 0, stream>>>(x2_f, big_f, ln3_g, ln3_bb, nullptr, actA, 0);

    // 11. logits = x3 @ proj_w.T  (3072 x 51865) -- deep-slack 2-barrier kernel
    run_cvt(proj_w, Wbf, (size_t)V * H, (size_t)VPAD * H, stream);
    {
        dim3 grid((NTOK / 256) * (VPAD / 256));   // 12 * 203 = 2436
        gemm8p<<<grid, 512, 0, stream>>>(actA, Wbf, out, H, V, V, NTOK / 256);
    }
}